// Round 1
// 97.038 us; speedup vs baseline: 1.0110x; 1.0110x over previous
//
#include <hip/hip_runtime.h>
#include <math.h>

#define NBATCH 256
#define NPTS   4096
#define NT     512
#define PPT    (NPTS / NT)          // 8 points per thread
#define NWAVE  (NT / 64)

// packed-lower index, r >= c
#define IDX(r,c)   ((r)*((r)+1)/2+(c))
// packed-upper index (reduction storage order), r <= c
#define UPIDX(r,c) ((r)*9 - ((r)*((r)-1))/2 + ((c)-(r)))

// fp64-internal 3x3 inverse of fp32 K, result to fp32
__device__ __forceinline__ void inv3x3f(const float* __restrict__ Km, float* Ki) {
  double a = Km[0], bb = Km[1], c = Km[2];
  double d = Km[3], e  = Km[4], f = Km[5];
  double g = Km[6], h  = Km[7], i = Km[8];
  double C00 =  e*i - f*h;
  double C01 = -(d*i - f*g);
  double C02 =  d*h - e*g;
  double det = a*C00 + bb*C01 + c*C02;
  double rd = 1.0/det;
  Ki[0] = (float)(C00*rd); Ki[1] = (float)(-(bb*i - c*h)*rd); Ki[2] = (float)( (bb*f - c*e)*rd);
  Ki[3] = (float)(C01*rd); Ki[4] = (float)( (a*i  - c*g)*rd); Ki[5] = (float)(-(a*f  - c*d)*rd);
  Ki[6] = (float)(C02*rd); Ki[7] = (float)(-(a*h - bb*g)*rd); Ki[8] = (float)( (a*e  - bb*d)*rd);
}

// ===========================================================================
// Fused, single-pass: block b = batch b.
//  Phase 1: float4 loads, normalize once, KEEP x0/x1/w in registers (fp32),
//           fp32 reduce of M -> fp64 cross-wave combine.
//           (Do NOT change NT or the reduction tree: fp32 sum order feeds the
//           near-tie argmax.)
//  Phase 2: fp64 solve. Cholesky serial on lane 0 (proven numerics), then the
//           three O(9^3) blocks (W=L^-1, B=W^T W, 20 power iters) are
//           LANE-PARALLEL over lanes 0..8 of wave 0 with BITWISE-IDENTICAL
//           arithmetic (zero-padded sums add exact +/-0 -> no-ops in RN;
//           IEEE multiply is bitwise commutative; __shfl moves exact bits).
//           Tail (normalize -> 6-sweep fp64 Jacobi -> U -> R1/R2) serial on
//           lane 0, unchanged.
//           NOTE: R4 (fp32 solve) and R6 (closed-form eig) both flipped the
//           candidate argmax in near-tie batches -> absmax ~2. Do not touch
//           the numerics, only the op-to-lane mapping.
//  Phase 3: cheirality scores from REGISTERS (no second global pass).
//  Phase 4: argmax + assemble T01/T10.
// ===========================================================================
__global__ __launch_bounds__(NT, 1)
void pose_fused(const float* __restrict__ kpts0,
                const float* __restrict__ kpts1,
                const float* __restrict__ conf,
                const float* __restrict__ t_scale,
                const float* __restrict__ Kmat,
                float* __restrict__ out)
{
  const int b    = blockIdx.x;
  const int tid  = threadIdx.x;
  const int lane = tid & 63;
  const int wv   = tid >> 6;

  __shared__ float  red[NWAVE][45];
  __shared__ double sMd[45];
  __shared__ double sLp[45];          // packed Cholesky L (lower)
  __shared__ double sDinv[9];         // 1/diag(L)
  __shared__ double sW[81];           // W = L^{-1} full 9x9: sW[k*9+j] = W[k][j]
  __shared__ float  sR[21];           // R1(9), R2(9), t(3)
  __shared__ float  sscore[NWAVE][4];

  float Ki0[9], Ki1[9];
  inv3x3f(Kmat + (size_t)b*18,     Ki0);
  inv3x3f(Kmat + (size_t)b*18 + 9, Ki1);

  const float4* k0p4 = (const float4*)(kpts0 + (size_t)b*NPTS*2);
  const float4* k1p4 = (const float4*)(kpts1 + (size_t)b*NPTS*2);
  const float2* cp2  = (const float2*)(conf  + (size_t)b*NPTS);

  // ---------------- Phase 1: load+normalize once, reduce M -----------------
  float px0[PPT][3], px1[PPT][3], pw[PPT];   // kept live into phase 3
  float acc[45];
#pragma unroll
  for (int j=0;j<45;j++) acc[j] = 0.f;

#pragma unroll
  for (int p=0;p<PPT/2;p++) {
    const int idx = tid + p*NT;          // float4 index: 2 points
    const float4 q0 = k0p4[idx];
    const float4 q1 = k1p4[idx];
    const float2 w2 = cp2[idx];
#pragma unroll
    for (int h=0; h<2; h++) {
      const int pt = 2*p + h;
      const float u0 = h ? q0.z : q0.x, v0 = h ? q0.w : q0.y;
      const float u1 = h ? q1.z : q1.x, v1 = h ? q1.w : q1.y;
      const float w  = h ? w2.y : w2.x;
      float x0[3], x1[3];
      x0[0] = fmaf(Ki0[0],u0, fmaf(Ki0[1],v0, Ki0[2]));
      x0[1] = fmaf(Ki0[3],u0, fmaf(Ki0[4],v0, Ki0[5]));
      x0[2] = fmaf(Ki0[6],u0, fmaf(Ki0[7],v0, Ki0[8]));
      x1[0] = fmaf(Ki1[0],u1, fmaf(Ki1[1],v1, Ki1[2]));
      x1[1] = fmaf(Ki1[3],u1, fmaf(Ki1[4],v1, Ki1[5]));
      x1[2] = fmaf(Ki1[6],u1, fmaf(Ki1[7],v1, Ki1[8]));
#pragma unroll
      for (int j=0;j<3;j++) { px0[pt][j] = x0[j]; px1[pt][j] = x1[j]; }
      pw[pt] = w;
      float X[9], wX[9];
#pragma unroll
      for (int ii=0; ii<3; ii++)
#pragma unroll
        for (int jj=0; jj<3; jj++)
          X[ii*3+jj] = x1[ii]*x0[jj];
#pragma unroll
      for (int j=0;j<9;j++) wX[j] = w*X[j];
      int k = 0;
#pragma unroll
      for (int r=0;r<9;r++)
#pragma unroll
        for (int c=r;c<9;c++) { acc[k] = fmaf(wX[r], X[c], acc[k]); k++; }
    }
  }

#pragma unroll
  for (int j=0;j<45;j++) {
    float v = acc[j];
#pragma unroll
    for (int off=32; off>0; off>>=1) v += __shfl_xor(v, off, 64);
    acc[j] = v;
  }
  if (lane == 0) {
#pragma unroll
    for (int j=0;j<45;j++) red[wv][j] = acc[j];
  }
  __syncthreads();
  if (tid < 45) {
    double s = 0.0;
#pragma unroll
    for (int wq=0; wq<NWAVE; wq++) s += (double)red[wq][tid];
    sMd[tid] = s;
  }
  __syncthreads();

  // ---------------- Phase 2: fp64 solve, 9-lane-parallel middle ------------
  if (wv == 0) {
    if (lane == 0) {
      double L[45];
#pragma unroll
      for (int r=0;r<9;r++)
#pragma unroll
        for (int c=0;c<=r;c++)
          L[IDX(r,c)] = sMd[UPIDX(c,r)];

      // Cholesky M = L L^T (packed lower, in place). M PD (lmin ~ 12).
      // UNCHANGED serial numerics.
      double dinv[9];
#pragma unroll
      for (int k=0;k<9;k++) {
        double s = L[IDX(k,k)];
#pragma unroll
        for (int j=0;j<k;j++) s -= L[IDX(k,j)]*L[IDX(k,j)];
        double l = sqrt(fmax(s, 1e-30));
        L[IDX(k,k)] = l;
        dinv[k] = 1.0/l;
#pragma unroll
        for (int i2=k+1;i2<9;i2++) {
          double s2 = L[IDX(i2,k)];
#pragma unroll
          for (int j=0;j<k;j++) s2 -= L[IDX(i2,j)]*L[IDX(k,j)];
          L[IDX(i2,k)] = s2*dinv[k];
        }
      }
      // publish L, dinv for the parallel lanes (L regs die here -> pressure ok)
#pragma unroll
      for (int j=0;j<45;j++) sLp[j] = L[j];
#pragma unroll
      for (int k=0;k<9;k++) sDinv[k] = dinv[k];
    }
    // wave-coherent LDS handoff (same wave; compiler can't see cross-lane dep)
    asm volatile("s_waitcnt lgkmcnt(0)" ::: "memory");
    __builtin_amdgcn_sched_barrier(0);

    double vlan[9];
    if (lane < 9) {
      // ---- W = L^{-1}, column `lane` via forward substitution. ----
      // Serial loop (col j outer, row i2 inner asc, k asc) == per-column
      // forward-sub: s = L[i2][j]*dinv[j] + sum_{k=j+1}^{i2-1} L[i2][k]*W[k][j].
      // Zero-padding k<j adds exact +/-0 terms (bitwise no-ops in RN);
      // fma(a,b,+0) == a*b bitwise.
      const double dj = sDinv[lane];
      double cw[9];
#pragma unroll
      for (int i=0;i<9;i++) cw[i] = (i == lane) ? dj : 0.0;
#pragma unroll
      for (int i2=1;i2<9;i2++) {
        double s = 0.0;
#pragma unroll
        for (int k=0;k<i2;k++) s = fma(sLp[IDX(i2,k)], cw[k], s);
        const double ci2 = -s*sDinv[i2];
        cw[i2] = (i2 > lane) ? ci2 : cw[i2];
      }
      // columns 0..8 jointly write all 81 entries (cw[k]=+0 for k<lane)
#pragma unroll
      for (int k=0;k<9;k++) sW[k*9 + lane] = cw[k];
    }
    asm volatile("s_waitcnt lgkmcnt(0)" ::: "memory");
    __builtin_amdgcn_sched_barrier(0);

    if (lane < 9) {
      // ---- B = W^T W = M^{-1}: row `lane`. ----
      // Element (r,c), r=max: serial is sum_{k=r}^{8} W[k][r]*W[k][c], k asc.
      // Ours: k from 0 with exact-zero terms until k=max, multiply operand
      // order swapped for c>r (bitwise commutative) -> bitwise identical.
      double wcol[9], Brow[9];
#pragma unroll
      for (int k=0;k<9;k++) wcol[k] = sW[k*9 + lane];
#pragma unroll
      for (int j=0;j<9;j++) {
        double s = 0.0;
#pragma unroll
        for (int k=0;k<9;k++) s = fma(wcol[k], sW[k*9 + j], s);
        Brow[j] = s;
      }

      // ---- 20 inverse-power iterations, row per lane. ----
      // y_i = sum_j fma(B[i][j], v[j]) j asc == serial; v gathered exactly
      // via __shfl (bit-moves). no renorm: fp64 exponent absorbs shrink.
      double vv[9];
#pragma unroll
      for (int j=0;j<9;j++) vv[j] = 0.125;
      vv[4] = 1.0;
      for (int it=0; it<20; ++it) {
        double y = 0.0;
#pragma unroll
        for (int j=0;j<9;j++) y = fma(Brow[j], vv[j], y);
#pragma unroll
        for (int j=0;j<9;j++) vv[j] = __shfl(y, j, 64);
      }
#pragma unroll
      for (int j=0;j<9;j++) vlan[j] = vv[j];
    }

    if (lane == 0) {
      // ---- serial tail (UNCHANGED numerics): normalize, Jacobi, U, R ----
      double v[9];
#pragma unroll
      for (int j=0;j<9;j++) v[j] = vlan[j];
      {
        double nn = 0.0;
#pragma unroll
        for (int j=0;j<9;j++) nn += v[j]*v[j];
        double rn = 1.0/sqrt(nn);
#pragma unroll
        for (int j=0;j<9;j++) v[j] *= rn;
      }

      // E = reshape(v,3,3); SVD: Jacobi on G=E^T E -> V; U via projection+cross
      double E0[3][3];
#pragma unroll
      for (int ii=0;ii<3;ii++)
#pragma unroll
        for (int jj=0;jj<3;jj++) E0[ii][jj] = v[ii*3+jj];
      double G[3][3];
#pragma unroll
      for (int a2=0;a2<3;a2++)
#pragma unroll
        for (int b2=0;b2<3;b2++)
          G[a2][b2] = E0[0][a2]*E0[0][b2] + E0[1][a2]*E0[1][b2] + E0[2][a2]*E0[2][b2];
      double Vv[3][3] = {{1,0,0},{0,1,0},{0,0,1}};
#define JROT(P,Q,RR) do { \
      double apq = G[P][Q]; \
      if (fabs(apq) > 1e-300) { \
        double app = G[P][P], aqq = G[Q][Q]; \
        double tau = (aqq - app) / (2.0*apq); \
        double tt = ((tau >= 0.0) ? 1.0 : -1.0) / (fabs(tau) + sqrt(1.0 + tau*tau)); \
        double cc_ = 1.0/sqrt(1.0 + tt*tt); \
        double ss_ = tt*cc_; \
        G[P][P] = app - tt*apq; \
        G[Q][Q] = aqq + tt*apq; \
        G[P][Q] = 0.0; G[Q][P] = 0.0; \
        double grp = G[RR][P], grq = G[RR][Q]; \
        G[RR][P] = cc_*grp - ss_*grq; G[P][RR] = G[RR][P]; \
        G[RR][Q] = ss_*grp + cc_*grq; G[Q][RR] = G[RR][Q]; \
        double v0p = Vv[0][P], v0q = Vv[0][Q]; \
        Vv[0][P] = cc_*v0p - ss_*v0q; Vv[0][Q] = ss_*v0p + cc_*v0q; \
        double v1p = Vv[1][P], v1q = Vv[1][Q]; \
        Vv[1][P] = cc_*v1p - ss_*v1q; Vv[1][Q] = ss_*v1p + cc_*v1q; \
        double v2p = Vv[2][P], v2q = Vv[2][Q]; \
        Vv[2][P] = cc_*v2p - ss_*v2q; Vv[2][Q] = ss_*v2p + cc_*v2q; \
      } } while(0)
      for (int sw=0; sw<6; sw++) { JROT(0,1,2); JROT(0,2,1); JROT(1,2,0); }
#undef JROT
      double lam[3] = {G[0][0], G[1][1], G[2][2]};
#define CSWAP(A_,B_) if (lam[A_] < lam[B_]) { \
      double tl = lam[A_]; lam[A_] = lam[B_]; lam[B_] = tl; \
      double t0_ = Vv[0][A_]; Vv[0][A_] = Vv[0][B_]; Vv[0][B_] = t0_; \
      double t1_ = Vv[1][A_]; Vv[1][A_] = Vv[1][B_]; Vv[1][B_] = t1_; \
      double t2_ = Vv[2][A_]; Vv[2][A_] = Vv[2][B_]; Vv[2][B_] = t2_; }
      CSWAP(0,1); CSWAP(0,2); CSWAP(1,2);
#undef CSWAP
      double u1[3], u2[3], u3[3];
#pragma unroll
      for (int i3=0;i3<3;i3++)
        u1[i3] = E0[i3][0]*Vv[0][0] + E0[i3][1]*Vv[1][0] + E0[i3][2]*Vv[2][0];
      double n1 = 1.0/sqrt(fmax(u1[0]*u1[0]+u1[1]*u1[1]+u1[2]*u1[2], 1e-300));
#pragma unroll
      for (int i3=0;i3<3;i3++) u1[i3] *= n1;
#pragma unroll
      for (int i3=0;i3<3;i3++)
        u2[i3] = E0[i3][0]*Vv[0][1] + E0[i3][1]*Vv[1][1] + E0[i3][2]*Vv[2][1];
      double d12 = u1[0]*u2[0]+u1[1]*u2[1]+u1[2]*u2[2];
#pragma unroll
      for (int i3=0;i3<3;i3++) u2[i3] -= d12*u1[i3];
      double n2 = 1.0/sqrt(fmax(u2[0]*u2[0]+u2[1]*u2[1]+u2[2]*u2[2], 1e-300));
#pragma unroll
      for (int i3=0;i3<3;i3++) u2[i3] *= n2;
      u3[0] = u1[1]*u2[2] - u1[2]*u2[1];
      u3[1] = u1[2]*u2[0] - u1[0]*u2[2];
      u3[2] = u1[0]*u2[1] - u1[1]*u2[0];
      // U W V^T = [u2,-u1,u3] V^T ;  U W^T V^T = [-u2,u1,u3] V^T
      double R1a[9], R2a[9];
#pragma unroll
      for (int i3=0;i3<3;i3++)
#pragma unroll
        for (int j3=0;j3<3;j3++) {
          double m  = u3[i3]*Vv[j3][2];
          double pA = u2[i3]*Vv[j3][0] - u1[i3]*Vv[j3][1];
          R1a[i3*3+j3] = pA + m;
          R2a[i3*3+j3] = m - pA;
        }
      double det1 = R1a[0]*(R1a[4]*R1a[8]-R1a[5]*R1a[7])
                  - R1a[1]*(R1a[3]*R1a[8]-R1a[5]*R1a[6])
                  + R1a[2]*(R1a[3]*R1a[7]-R1a[4]*R1a[6]);
      double det2 = R2a[0]*(R2a[4]*R2a[8]-R2a[5]*R2a[7])
                  - R2a[1]*(R2a[3]*R2a[8]-R2a[5]*R2a[6])
                  + R2a[2]*(R2a[3]*R2a[7]-R2a[4]*R2a[6]);
      double sg1 = (det1 < 0.0) ? -1.0 : 1.0;
      double sg2 = (det2 < 0.0) ? -1.0 : 1.0;
#pragma unroll
      for (int j3=0;j3<9;j3++) { sR[j3] = (float)(sg1*R1a[j3]); sR[9+j3] = (float)(sg2*R2a[j3]); }
      sR[18] = (float)u3[0]; sR[19] = (float)u3[1]; sR[20] = (float)u3[2];
    }
  }
  __syncthreads();

  // ---------------- Phase 3: cheirality scores from registers --------------
  float r1[9], r2[9], tv[3];
#pragma unroll
  for (int j=0;j<9;j++) { r1[j] = sR[j]; r2[j] = sR[9+j]; }
  tv[0] = sR[18]; tv[1] = sR[19]; tv[2] = sR[20];

  float sc[4] = {0.f, 0.f, 0.f, 0.f};
#pragma unroll
  for (int p=0;p<PPT;p++) {
    const float x00 = px0[p][0], x01 = px0[p][1], x02 = px0[p][2];
    const float x10 = px1[p][0], x11 = px1[p][1], x12 = px1[p][2];
    const float w   = pw[p];
    const float bb2 = x10*x10 + x11*x11 + x12*x12;
    const float bt  = x10*tv[0] + x11*tv[1] + x12*tv[2];
    {
      float a0 = r1[0]*x00 + r1[1]*x01 + r1[2]*x02;
      float a1 = r1[3]*x00 + r1[4]*x01 + r1[5]*x02;
      float a2 = r1[6]*x00 + r1[7]*x01 + r1[8]*x02;
      float aa = a0*a0 + a1*a1 + a2*a2;
      float ab = a0*x10 + a1*x11 + a2*x12;
      float at = a0*tv[0] + a1*tv[1] + a2*tv[2];
      float n0v = ab*bt - at*bb2;     // d0*det (det>0)
      float n1v = aa*bt - ab*at;      // d1*det
      if (n0v > 0.f && n1v > 0.f) sc[0] += w;    // (R1,+t)
      if (n0v < 0.f && n1v < 0.f) sc[1] += w;    // (R1,-t)
    }
    {
      float a0 = r2[0]*x00 + r2[1]*x01 + r2[2]*x02;
      float a1 = r2[3]*x00 + r2[4]*x01 + r2[5]*x02;
      float a2 = r2[6]*x00 + r2[7]*x01 + r2[8]*x02;
      float aa = a0*a0 + a1*a1 + a2*a2;
      float ab = a0*x10 + a1*x11 + a2*x12;
      float at = a0*tv[0] + a1*tv[1] + a2*tv[2];
      float n0v = ab*bt - at*bb2;
      float n1v = aa*bt - ab*at;
      if (n0v > 0.f && n1v > 0.f) sc[2] += w;    // (R2,+t)
      if (n0v < 0.f && n1v < 0.f) sc[3] += w;    // (R2,-t)
    }
  }
#pragma unroll
  for (int c=0;c<4;c++) {
    float vv = sc[c];
#pragma unroll
    for (int off=32; off>0; off>>=1) vv += __shfl_xor(vv, off, 64);
    sc[c] = vv;
  }
  if (lane == 0) {
#pragma unroll
    for (int c=0;c<4;c++) sscore[wv][c] = sc[c];
  }
  __syncthreads();

  // ---------------- Phase 4 (tid 0): argmax + assemble T01/T10 -------------
  if (tid == 0) {
    float st[4];
#pragma unroll
    for (int c=0;c<4;c++) {
      float s = 0.f;
#pragma unroll
      for (int wq=0; wq<NWAVE; wq++) s += sscore[wq][c];
      st[c] = s;
    }
    int bestc = 0; float bs = st[0];
    if (st[1] > bs) { bs = st[1]; bestc = 1; }   // strict > keeps first on tie
    if (st[2] > bs) { bs = st[2]; bestc = 2; }
    if (st[3] > bs) { bs = st[3]; bestc = 3; }
    float Rb[9];
#pragma unroll
    for (int j=0;j<9;j++) Rb[j] = (bestc < 2) ? r1[j] : r2[j];
    const float sg = (bestc & 1) ? -1.f : 1.f;
    const float ts = t_scale[(size_t)b*2];
    const float t0 = sg*tv[0]*ts, t1 = sg*tv[1]*ts, t2 = sg*tv[2]*ts;
    float* o = out + (size_t)b*32;
    // T01 = [R | t_sc ; 0 0 0 1]
    o[0]=Rb[0]; o[1]=Rb[1]; o[2] =Rb[2]; o[3] =t0;
    o[4]=Rb[3]; o[5]=Rb[4]; o[6] =Rb[5]; o[7] =t1;
    o[8]=Rb[6]; o[9]=Rb[7]; o[10]=Rb[8]; o[11]=t2;
    o[12]=0.f; o[13]=0.f; o[14]=0.f; o[15]=1.f;
    // T10 = [R^T | -R^T t_sc ; 0 0 0 1]
    const float ti0 = -(Rb[0]*t0 + Rb[3]*t1 + Rb[6]*t2);
    const float ti1 = -(Rb[1]*t0 + Rb[4]*t1 + Rb[7]*t2);
    const float ti2 = -(Rb[2]*t0 + Rb[5]*t1 + Rb[8]*t2);
    o[16]=Rb[0]; o[17]=Rb[3]; o[18]=Rb[6]; o[19]=ti0;
    o[20]=Rb[1]; o[21]=Rb[4]; o[22]=Rb[7]; o[23]=ti1;
    o[24]=Rb[2]; o[25]=Rb[5]; o[26]=Rb[8]; o[27]=ti2;
    o[28]=0.f; o[29]=0.f; o[30]=0.f; o[31]=1.f;
  }
}

// ===========================================================================
extern "C" void kernel_launch(void* const* d_in, const int* in_sizes, int n_in,
                              void* d_out, int out_size, void* d_ws, size_t ws_size,
                              hipStream_t stream) {
  (void)in_sizes; (void)n_in; (void)out_size; (void)d_ws; (void)ws_size;
  const float* kpts0  = (const float*)d_in[0];
  const float* kpts1  = (const float*)d_in[1];
  const float* conf   = (const float*)d_in[2];
  const float* tscale = (const float*)d_in[3];
  const float* K      = (const float*)d_in[4];
  float* outp = (float*)d_out;
  pose_fused<<<dim3(NBATCH), dim3(NT), 0, stream>>>(kpts0, kpts1, conf, tscale, K, outp);
}

// Round 2
// 94.453 us; speedup vs baseline: 1.0387x; 1.0274x over previous
//
#include <hip/hip_runtime.h>
#include <math.h>

#define NBATCH 256
#define NPTS   4096
#define NT     512
#define PPT    (NPTS / NT)          // 8 points per thread
#define NWAVE  (NT / 64)

// packed-lower index, r >= c
#define IDX(r,c)   ((r)*((r)+1)/2+(c))
// packed-upper index (reduction storage order), r <= c
#define UPIDX(r,c) ((r)*9 - ((r)*((r)-1))/2 + ((c)-(r)))

// fp64-internal 3x3 inverse of fp32 K, result to fp32
__device__ __forceinline__ void inv3x3f(const float* __restrict__ Km, float* Ki) {
  double a = Km[0], bb = Km[1], c = Km[2];
  double d = Km[3], e  = Km[4], f = Km[5];
  double g = Km[6], h  = Km[7], i = Km[8];
  double C00 =  e*i - f*h;
  double C01 = -(d*i - f*g);
  double C02 =  d*h - e*g;
  double det = a*C00 + bb*C01 + c*C02;
  double rd = 1.0/det;
  Ki[0] = (float)(C00*rd); Ki[1] = (float)(-(bb*i - c*h)*rd); Ki[2] = (float)( (bb*f - c*e)*rd);
  Ki[3] = (float)(C01*rd); Ki[4] = (float)( (a*i  - c*g)*rd); Ki[5] = (float)(-(a*f  - c*d)*rd);
  Ki[6] = (float)(C02*rd); Ki[7] = (float)(-(a*h - bb*g)*rd); Ki[8] = (float)( (a*e  - bb*d)*rd);
}

// ===========================================================================
// Fused, single-pass: block b = batch b.
//  Phase 1: float4 loads, normalize once, KEEP x0/x1/w in registers (fp32),
//           fp32 reduce of M -> fp64 cross-wave combine.
//           (Do NOT change NT or the reduction tree: fp32 sum order feeds the
//           near-tie argmax. fp32-scale (1e-7) perturbations are proven
//           dangerous; fp64-scale (1e-15) reassociations are allowed.)
//  Phase 2: fp64 solve. Cholesky serial on lane 0 (proven numerics); W=L^-1,
//           B=W^T W lane-parallel over lanes 0..8 (bitwise-identical to the
//           serial order). Power iteration: v <- (B*B)^10 v (== B^20 v up to
//           fp64 reassociation ~1e-16; halves the dependent-chain rounds).
//           Jacobi: 6 sweeps with a 1e-18 RELATIVE skip guard -- rotations
//           below that are sub-ULP no-ops on V (quadratic convergence makes
//           sweeps ~5-6 all skips). Tail (U, R1/R2) serial, unchanged.
//           NOTE: R4 (fp32 solve) and R6 (closed-form eig) both flipped the
//           candidate argmax in near-tie batches -> absmax ~2. Algorithm
//           structure and all fp32 paths stay untouched.
//  Phase 3: cheirality scores from REGISTERS (no second global pass).
//  Phase 4: argmax + assemble T01/T10.
// ===========================================================================
__global__ __launch_bounds__(NT, 1)
void pose_fused(const float* __restrict__ kpts0,
                const float* __restrict__ kpts1,
                const float* __restrict__ conf,
                const float* __restrict__ t_scale,
                const float* __restrict__ Kmat,
                float* __restrict__ out)
{
  const int b    = blockIdx.x;
  const int tid  = threadIdx.x;
  const int lane = tid & 63;
  const int wv   = tid >> 6;

  __shared__ float  red[NWAVE][45];
  __shared__ double sMd[45];
  __shared__ double sLp[45];          // packed Cholesky L (lower)
  __shared__ double sDinv[9];         // 1/diag(L)
  __shared__ double sW[81];           // W = L^{-1} full 9x9: sW[k*9+j] = W[k][j]
  __shared__ double sB[81];           // B = M^{-1} (row-major), for squaring
  __shared__ float  sR[21];           // R1(9), R2(9), t(3)
  __shared__ float  sscore[NWAVE][4];

  float Ki0[9], Ki1[9];
  inv3x3f(Kmat + (size_t)b*18,     Ki0);
  inv3x3f(Kmat + (size_t)b*18 + 9, Ki1);

  const float4* k0p4 = (const float4*)(kpts0 + (size_t)b*NPTS*2);
  const float4* k1p4 = (const float4*)(kpts1 + (size_t)b*NPTS*2);
  const float2* cp2  = (const float2*)(conf  + (size_t)b*NPTS);

  // ---------------- Phase 1: load+normalize once, reduce M -----------------
  float px0[PPT][3], px1[PPT][3], pw[PPT];   // kept live into phase 3
  float acc[45];
#pragma unroll
  for (int j=0;j<45;j++) acc[j] = 0.f;

#pragma unroll
  for (int p=0;p<PPT/2;p++) {
    const int idx = tid + p*NT;          // float4 index: 2 points
    const float4 q0 = k0p4[idx];
    const float4 q1 = k1p4[idx];
    const float2 w2 = cp2[idx];
#pragma unroll
    for (int h=0; h<2; h++) {
      const int pt = 2*p + h;
      const float u0 = h ? q0.z : q0.x, v0 = h ? q0.w : q0.y;
      const float u1 = h ? q1.z : q1.x, v1 = h ? q1.w : q1.y;
      const float w  = h ? w2.y : w2.x;
      float x0[3], x1[3];
      x0[0] = fmaf(Ki0[0],u0, fmaf(Ki0[1],v0, Ki0[2]));
      x0[1] = fmaf(Ki0[3],u0, fmaf(Ki0[4],v0, Ki0[5]));
      x0[2] = fmaf(Ki0[6],u0, fmaf(Ki0[7],v0, Ki0[8]));
      x1[0] = fmaf(Ki1[0],u1, fmaf(Ki1[1],v1, Ki1[2]));
      x1[1] = fmaf(Ki1[3],u1, fmaf(Ki1[4],v1, Ki1[5]));
      x1[2] = fmaf(Ki1[6],u1, fmaf(Ki1[7],v1, Ki1[8]));
#pragma unroll
      for (int j=0;j<3;j++) { px0[pt][j] = x0[j]; px1[pt][j] = x1[j]; }
      pw[pt] = w;
      float X[9], wX[9];
#pragma unroll
      for (int ii=0; ii<3; ii++)
#pragma unroll
        for (int jj=0; jj<3; jj++)
          X[ii*3+jj] = x1[ii]*x0[jj];
#pragma unroll
      for (int j=0;j<9;j++) wX[j] = w*X[j];
      int k = 0;
#pragma unroll
      for (int r=0;r<9;r++)
#pragma unroll
        for (int c=r;c<9;c++) { acc[k] = fmaf(wX[r], X[c], acc[k]); k++; }
    }
  }

#pragma unroll
  for (int j=0;j<45;j++) {
    float v = acc[j];
#pragma unroll
    for (int off=32; off>0; off>>=1) v += __shfl_xor(v, off, 64);
    acc[j] = v;
  }
  if (lane == 0) {
#pragma unroll
    for (int j=0;j<45;j++) red[wv][j] = acc[j];
  }
  __syncthreads();
  if (tid < 45) {
    double s = 0.0;
#pragma unroll
    for (int wq=0; wq<NWAVE; wq++) s += (double)red[wq][tid];
    sMd[tid] = s;
  }
  __syncthreads();

  // ---------------- Phase 2: fp64 solve, 9-lane-parallel middle ------------
  if (wv == 0) {
    if (lane == 0) {
      double L[45];
#pragma unroll
      for (int r=0;r<9;r++)
#pragma unroll
        for (int c=0;c<=r;c++)
          L[IDX(r,c)] = sMd[UPIDX(c,r)];

      // Cholesky M = L L^T (packed lower, in place). M PD (lmin ~ 12).
      // UNCHANGED serial numerics.
      double dinv[9];
#pragma unroll
      for (int k=0;k<9;k++) {
        double s = L[IDX(k,k)];
#pragma unroll
        for (int j=0;j<k;j++) s -= L[IDX(k,j)]*L[IDX(k,j)];
        double l = sqrt(fmax(s, 1e-30));
        L[IDX(k,k)] = l;
        dinv[k] = 1.0/l;
#pragma unroll
        for (int i2=k+1;i2<9;i2++) {
          double s2 = L[IDX(i2,k)];
#pragma unroll
          for (int j=0;j<k;j++) s2 -= L[IDX(i2,j)]*L[IDX(k,j)];
          L[IDX(i2,k)] = s2*dinv[k];
        }
      }
      // publish L, dinv for the parallel lanes (L regs die here -> pressure ok)
#pragma unroll
      for (int j=0;j<45;j++) sLp[j] = L[j];
#pragma unroll
      for (int k=0;k<9;k++) sDinv[k] = dinv[k];
    }
    // wave-coherent LDS handoff (same wave; compiler can't see cross-lane dep)
    asm volatile("s_waitcnt lgkmcnt(0)" ::: "memory");
    __builtin_amdgcn_sched_barrier(0);

    double Brow[9];
    double vlan[9];
    if (lane < 9) {
      // ---- W = L^{-1}, column `lane` via forward substitution. ----
      // Bitwise-identical to serial (zero-padded terms are exact +/-0 no-ops).
      const double dj = sDinv[lane];
      double cw[9];
#pragma unroll
      for (int i=0;i<9;i++) cw[i] = (i == lane) ? dj : 0.0;
#pragma unroll
      for (int i2=1;i2<9;i2++) {
        double s = 0.0;
#pragma unroll
        for (int k=0;k<i2;k++) s = fma(sLp[IDX(i2,k)], cw[k], s);
        const double ci2 = -s*sDinv[i2];
        cw[i2] = (i2 > lane) ? ci2 : cw[i2];
      }
      // columns 0..8 jointly write all 81 entries (cw[k]=+0 for k<lane)
#pragma unroll
      for (int k=0;k<9;k++) sW[k*9 + lane] = cw[k];
    }
    asm volatile("s_waitcnt lgkmcnt(0)" ::: "memory");
    __builtin_amdgcn_sched_barrier(0);

    if (lane < 9) {
      // ---- B = W^T W = M^{-1}: row `lane` (bitwise == serial order). ----
      double wcol[9];
#pragma unroll
      for (int k=0;k<9;k++) wcol[k] = sW[k*9 + lane];
#pragma unroll
      for (int j=0;j<9;j++) {
        double s = 0.0;
#pragma unroll
        for (int k=0;k<9;k++) s = fma(wcol[k], sW[k*9 + j], s);
        Brow[j] = s;
      }
      // publish B for the squaring step
#pragma unroll
      for (int j=0;j<9;j++) sB[lane*9 + j] = Brow[j];
    }
    asm volatile("s_waitcnt lgkmcnt(0)" ::: "memory");
    __builtin_amdgcn_sched_barrier(0);

    if (lane < 9) {
      // ---- C = B*B (row `lane`): one extra 9x9x9 matmul, lane-parallel. ----
      // NEW vs R0: v <- C^10 v replaces v <- B^20 v. Same operator to within
      // fp64 reassociation (~1e-16 rel) -- 8 orders below the proven-danger
      // fp32 scale; halves the dependent chain+broadcast rounds.
      double Crow[9];
#pragma unroll
      for (int j=0;j<9;j++) {
        double s = 0.0;
#pragma unroll
        for (int k=0;k<9;k++) s = fma(Brow[k], sB[k*9 + j], s);
        Crow[j] = s;
      }

      // ---- 10 inverse-power rounds with C, row per lane. ----
      // Tree dot (4-level) cuts per-round latency; no renorm needed: fp64
      // exponent absorbs the shrink (|v| ~ 0.007^10 ~ 1e-22, no underflow).
      double vv[9];
#pragma unroll
      for (int j=0;j<9;j++) vv[j] = 0.125;
      vv[4] = 1.0;
      for (int it=0; it<10; ++it) {
        double p0 = fma(Crow[1], vv[1], Crow[0]*vv[0]);
        double p1 = fma(Crow[3], vv[3], Crow[2]*vv[2]);
        double p2 = fma(Crow[5], vv[5], Crow[4]*vv[4]);
        double p3 = fma(Crow[7], vv[7], Crow[6]*vv[6]);
        double p4 = Crow[8]*vv[8];
        double y  = ((p0 + p1) + (p2 + p3)) + p4;
#pragma unroll
        for (int j=0;j<9;j++) vv[j] = __shfl(y, j, 64);
      }
#pragma unroll
      for (int j=0;j<9;j++) vlan[j] = vv[j];
    }

    if (lane == 0) {
      // ---- serial tail: normalize, Jacobi, U, R (structure unchanged) ----
      double v[9];
#pragma unroll
      for (int j=0;j<9;j++) v[j] = vlan[j];
      {
        double nn = 0.0;
#pragma unroll
        for (int j=0;j<9;j++) nn += v[j]*v[j];
        double rn = 1.0/sqrt(nn);
#pragma unroll
        for (int j=0;j<9;j++) v[j] *= rn;
      }

      // E = reshape(v,3,3); SVD: Jacobi on G=E^T E -> V; U via projection+cross
      double E0[3][3];
#pragma unroll
      for (int ii=0;ii<3;ii++)
#pragma unroll
        for (int jj=0;jj<3;jj++) E0[ii][jj] = v[ii*3+jj];
      double G[3][3];
#pragma unroll
      for (int a2=0;a2<3;a2++)
#pragma unroll
        for (int b2=0;b2<3;b2++)
          G[a2][b2] = E0[0][a2]*E0[0][b2] + E0[1][a2]*E0[1][b2] + E0[2][a2]*E0[2][b2];
      double Vv[3][3] = {{1,0,0},{0,1,0},{0,0,1}};
      // Skip guard is RELATIVE (1e-18): rotations below it change V by
      // < 1e-18 rel (sub-ULP). Quadratic convergence => sweeps ~5-6 all skip,
      // saving ~6-8 of the 18 div/sqrt dependent chains (~180 cyc each).
      // G is PSD so |apq| <= (app+aqq)/2; guard is scale-correct.
#define JROT(P,Q,RR) do { \
      double apq = G[P][Q]; \
      if (fabs(apq) > 1e-18*(fabs(G[P][P])+fabs(G[Q][Q]))) { \
        double app = G[P][P], aqq = G[Q][Q]; \
        double tau = (aqq - app) / (2.0*apq); \
        double tt = ((tau >= 0.0) ? 1.0 : -1.0) / (fabs(tau) + sqrt(1.0 + tau*tau)); \
        double cc_ = 1.0/sqrt(1.0 + tt*tt); \
        double ss_ = tt*cc_; \
        G[P][P] = app - tt*apq; \
        G[Q][Q] = aqq + tt*apq; \
        G[P][Q] = 0.0; G[Q][P] = 0.0; \
        double grp = G[RR][P], grq = G[RR][Q]; \
        G[RR][P] = cc_*grp - ss_*grq; G[P][RR] = G[RR][P]; \
        G[RR][Q] = ss_*grp + cc_*grq; G[Q][RR] = G[RR][Q]; \
        double v0p = Vv[0][P], v0q = Vv[0][Q]; \
        Vv[0][P] = cc_*v0p - ss_*v0q; Vv[0][Q] = ss_*v0p + cc_*v0q; \
        double v1p = Vv[1][P], v1q = Vv[1][Q]; \
        Vv[1][P] = cc_*v1p - ss_*v1q; Vv[1][Q] = ss_*v1p + cc_*v1q; \
        double v2p = Vv[2][P], v2q = Vv[2][Q]; \
        Vv[2][P] = cc_*v2p - ss_*v2q; Vv[2][Q] = ss_*v2p + cc_*v2q; \
      } } while(0)
      for (int sw=0; sw<6; sw++) { JROT(0,1,2); JROT(0,2,1); JROT(1,2,0); }
#undef JROT
      double lam[3] = {G[0][0], G[1][1], G[2][2]};
#define CSWAP(A_,B_) if (lam[A_] < lam[B_]) { \
      double tl = lam[A_]; lam[A_] = lam[B_]; lam[B_] = tl; \
      double t0_ = Vv[0][A_]; Vv[0][A_] = Vv[0][B_]; Vv[0][B_] = t0_; \
      double t1_ = Vv[1][A_]; Vv[1][A_] = Vv[1][B_]; Vv[1][B_] = t1_; \
      double t2_ = Vv[2][A_]; Vv[2][A_] = Vv[2][B_]; Vv[2][B_] = t2_; }
      CSWAP(0,1); CSWAP(0,2); CSWAP(1,2);
#undef CSWAP
      double u1[3], u2[3], u3[3];
#pragma unroll
      for (int i3=0;i3<3;i3++)
        u1[i3] = E0[i3][0]*Vv[0][0] + E0[i3][1]*Vv[1][0] + E0[i3][2]*Vv[2][0];
      double n1 = 1.0/sqrt(fmax(u1[0]*u1[0]+u1[1]*u1[1]+u1[2]*u1[2], 1e-300));
#pragma unroll
      for (int i3=0;i3<3;i3++) u1[i3] *= n1;
#pragma unroll
      for (int i3=0;i3<3;i3++)
        u2[i3] = E0[i3][0]*Vv[0][1] + E0[i3][1]*Vv[1][1] + E0[i3][2]*Vv[2][1];
      double d12 = u1[0]*u2[0]+u1[1]*u2[1]+u1[2]*u2[2];
#pragma unroll
      for (int i3=0;i3<3;i3++) u2[i3] -= d12*u1[i3];
      double n2 = 1.0/sqrt(fmax(u2[0]*u2[0]+u2[1]*u2[1]+u2[2]*u2[2], 1e-300));
#pragma unroll
      for (int i3=0;i3<3;i3++) u2[i3] *= n2;
      u3[0] = u1[1]*u2[2] - u1[2]*u2[1];
      u3[1] = u1[2]*u2[0] - u1[0]*u2[2];
      u3[2] = u1[0]*u2[1] - u1[1]*u2[0];
      // U W V^T = [u2,-u1,u3] V^T ;  U W^T V^T = [-u2,u1,u3] V^T
      double R1a[9], R2a[9];
#pragma unroll
      for (int i3=0;i3<3;i3++)
#pragma unroll
        for (int j3=0;j3<3;j3++) {
          double m  = u3[i3]*Vv[j3][2];
          double pA = u2[i3]*Vv[j3][0] - u1[i3]*Vv[j3][1];
          R1a[i3*3+j3] = pA + m;
          R2a[i3*3+j3] = m - pA;
        }
      double det1 = R1a[0]*(R1a[4]*R1a[8]-R1a[5]*R1a[7])
                  - R1a[1]*(R1a[3]*R1a[8]-R1a[5]*R1a[6])
                  + R1a[2]*(R1a[3]*R1a[7]-R1a[4]*R1a[6]);
      double det2 = R2a[0]*(R2a[4]*R2a[8]-R2a[5]*R2a[7])
                  - R2a[1]*(R2a[3]*R2a[8]-R2a[5]*R2a[6])
                  + R2a[2]*(R2a[3]*R2a[7]-R2a[4]*R2a[6]);
      double sg1 = (det1 < 0.0) ? -1.0 : 1.0;
      double sg2 = (det2 < 0.0) ? -1.0 : 1.0;
#pragma unroll
      for (int j3=0;j3<9;j3++) { sR[j3] = (float)(sg1*R1a[j3]); sR[9+j3] = (float)(sg2*R2a[j3]); }
      sR[18] = (float)u3[0]; sR[19] = (float)u3[1]; sR[20] = (float)u3[2];
    }
  }
  __syncthreads();

  // ---------------- Phase 3: cheirality scores from registers --------------
  float r1[9], r2[9], tv[3];
#pragma unroll
  for (int j=0;j<9;j++) { r1[j] = sR[j]; r2[j] = sR[9+j]; }
  tv[0] = sR[18]; tv[1] = sR[19]; tv[2] = sR[20];

  float sc[4] = {0.f, 0.f, 0.f, 0.f};
#pragma unroll
  for (int p=0;p<PPT;p++) {
    const float x00 = px0[p][0], x01 = px0[p][1], x02 = px0[p][2];
    const float x10 = px1[p][0], x11 = px1[p][1], x12 = px1[p][2];
    const float w   = pw[p];
    const float bb2 = x10*x10 + x11*x11 + x12*x12;
    const float bt  = x10*tv[0] + x11*tv[1] + x12*tv[2];
    {
      float a0 = r1[0]*x00 + r1[1]*x01 + r1[2]*x02;
      float a1 = r1[3]*x00 + r1[4]*x01 + r1[5]*x02;
      float a2 = r1[6]*x00 + r1[7]*x01 + r1[8]*x02;
      float aa = a0*a0 + a1*a1 + a2*a2;
      float ab = a0*x10 + a1*x11 + a2*x12;
      float at = a0*tv[0] + a1*tv[1] + a2*tv[2];
      float n0v = ab*bt - at*bb2;     // d0*det (det>0)
      float n1v = aa*bt - ab*at;      // d1*det
      if (n0v > 0.f && n1v > 0.f) sc[0] += w;    // (R1,+t)
      if (n0v < 0.f && n1v < 0.f) sc[1] += w;    // (R1,-t)
    }
    {
      float a0 = r2[0]*x00 + r2[1]*x01 + r2[2]*x02;
      float a1 = r2[3]*x00 + r2[4]*x01 + r2[5]*x02;
      float a2 = r2[6]*x00 + r2[7]*x01 + r2[8]*x02;
      float aa = a0*a0 + a1*a1 + a2*a2;
      float ab = a0*x10 + a1*x11 + a2*x12;
      float at = a0*tv[0] + a1*tv[1] + a2*tv[2];
      float n0v = ab*bt - at*bb2;
      float n1v = aa*bt - ab*at;
      if (n0v > 0.f && n1v > 0.f) sc[2] += w;    // (R2,+t)
      if (n0v < 0.f && n1v < 0.f) sc[3] += w;    // (R2,-t)
    }
  }
#pragma unroll
  for (int c=0;c<4;c++) {
    float vv = sc[c];
#pragma unroll
    for (int off=32; off>0; off>>=1) vv += __shfl_xor(vv, off, 64);
    sc[c] = vv;
  }
  if (lane == 0) {
#pragma unroll
    for (int c=0;c<4;c++) sscore[wv][c] = sc[c];
  }
  __syncthreads();

  // ---------------- Phase 4 (tid 0): argmax + assemble T01/T10 -------------
  if (tid == 0) {
    float st[4];
#pragma unroll
    for (int c=0;c<4;c++) {
      float s = 0.f;
#pragma unroll
      for (int wq=0; wq<NWAVE; wq++) s += sscore[wq][c];
      st[c] = s;
    }
    int bestc = 0; float bs = st[0];
    if (st[1] > bs) { bs = st[1]; bestc = 1; }   // strict > keeps first on tie
    if (st[2] > bs) { bs = st[2]; bestc = 2; }
    if (st[3] > bs) { bs = st[3]; bestc = 3; }
    float Rb[9];
#pragma unroll
    for (int j=0;j<9;j++) Rb[j] = (bestc < 2) ? r1[j] : r2[j];
    const float sg = (bestc & 1) ? -1.f : 1.f;
    const float ts = t_scale[(size_t)b*2];
    const float t0 = sg*tv[0]*ts, t1 = sg*tv[1]*ts, t2 = sg*tv[2]*ts;
    float* o = out + (size_t)b*32;
    // T01 = [R | t_sc ; 0 0 0 1]
    o[0]=Rb[0]; o[1]=Rb[1]; o[2] =Rb[2]; o[3] =t0;
    o[4]=Rb[3]; o[5]=Rb[4]; o[6] =Rb[5]; o[7] =t1;
    o[8]=Rb[6]; o[9]=Rb[7]; o[10]=Rb[8]; o[11]=t2;
    o[12]=0.f; o[13]=0.f; o[14]=0.f; o[15]=1.f;
    // T10 = [R^T | -R^T t_sc ; 0 0 0 1]
    const float ti0 = -(Rb[0]*t0 + Rb[3]*t1 + Rb[6]*t2);
    const float ti1 = -(Rb[1]*t0 + Rb[4]*t1 + Rb[7]*t2);
    const float ti2 = -(Rb[2]*t0 + Rb[5]*t1 + Rb[8]*t2);
    o[16]=Rb[0]; o[17]=Rb[3]; o[18]=Rb[6]; o[19]=ti0;
    o[20]=Rb[1]; o[21]=Rb[4]; o[22]=Rb[7]; o[23]=ti1;
    o[24]=Rb[2]; o[25]=Rb[5]; o[26]=Rb[8]; o[27]=ti2;
    o[28]=0.f; o[29]=0.f; o[30]=0.f; o[31]=1.f;
  }
}

// ===========================================================================
extern "C" void kernel_launch(void* const* d_in, const int* in_sizes, int n_in,
                              void* d_out, int out_size, void* d_ws, size_t ws_size,
                              hipStream_t stream) {
  (void)in_sizes; (void)n_in; (void)out_size; (void)d_ws; (void)ws_size;
  const float* kpts0  = (const float*)d_in[0];
  const float* kpts1  = (const float*)d_in[1];
  const float* conf   = (const float*)d_in[2];
  const float* tscale = (const float*)d_in[3];
  const float* K      = (const float*)d_in[4];
  float* outp = (float*)d_out;
  pose_fused<<<dim3(NBATCH), dim3(NT), 0, stream>>>(kpts0, kpts1, conf, tscale, K, outp);
}

// Round 3
// 92.716 us; speedup vs baseline: 1.0581x; 1.0187x over previous
//
#include <hip/hip_runtime.h>
#include <math.h>

#define NBATCH 256
#define NPTS   4096
#define NT     512
#define PPT    (NPTS / NT)          // 8 points per thread
#define NWAVE  (NT / 64)

// packed-lower index, r >= c
#define IDX(r,c)   ((r)*((r)+1)/2+(c))
// packed-upper index (reduction storage order), r <= c
#define UPIDX(r,c) ((r)*9 - ((r)*((r)-1))/2 + ((c)-(r)))

// fp64-internal 3x3 inverse of fp32 K, result to fp32
__device__ __forceinline__ void inv3x3f(const float* __restrict__ Km, float* Ki) {
  double a = Km[0], bb = Km[1], c = Km[2];
  double d = Km[3], e  = Km[4], f = Km[5];
  double g = Km[6], h  = Km[7], i = Km[8];
  double C00 =  e*i - f*h;
  double C01 = -(d*i - f*g);
  double C02 =  d*h - e*g;
  double det = a*C00 + bb*C01 + c*C02;
  double rd = 1.0/det;
  Ki[0] = (float)(C00*rd); Ki[1] = (float)(-(bb*i - c*h)*rd); Ki[2] = (float)( (bb*f - c*e)*rd);
  Ki[3] = (float)(C01*rd); Ki[4] = (float)( (a*i  - c*g)*rd); Ki[5] = (float)(-(a*f  - c*d)*rd);
  Ki[6] = (float)(C02*rd); Ki[7] = (float)(-(a*h - bb*g)*rd); Ki[8] = (float)( (a*e  - bb*d)*rd);
}

// ===========================================================================
// Fused, single-pass: block b = batch b.
//  NUMERICS POLICY (validated R1->R2 bench: absmax bitwise-stable):
//    - fp32 paths (phase-1 reduction tree, phase-3 scoring) are UNTOUCHABLE:
//      1e-7-scale perturbation flips near-tie argmax (R4/R6 -> absmax ~2).
//    - fp64 reassociation at ~1e-16 rel IS allowed (C=B*B squaring passed).
//  Phase 1: float4 loads, normalize once, x0/x1/w stay in registers.
//  Phase 2: fp64 solve on wave 0.
//    - cross-wave combine on lanes 0..44 (wave-coherent handoff, no barrier)
//    - LDL^T factorization on lane 0 (no sqrt on the critical path; 1e-16
//      class vs LL^T)
//    - W=L^{-1} (unit lower), B=W^T D^{-1} W lane-parallel (lanes 0..8)
//    - v <- (B^4)^5 v  == B^20 v up to reassociation (2 squarings, 5 rounds)
//    - no v normalization (Jacobi scale-invariant; u's renormalized; |v|^2
//      ~1e-44 >> denormal floor)
//    - 6-sweep Jacobi with 1e-18 RELATIVE skip guard; serial tail on lane 0.
//  Phase 3: cheirality scores from registers.
//  Phase 4: argmax + assemble T01/T10.
// ===========================================================================
__global__ __launch_bounds__(NT, 1)
void pose_fused(const float* __restrict__ kpts0,
                const float* __restrict__ kpts1,
                const float* __restrict__ conf,
                const float* __restrict__ t_scale,
                const float* __restrict__ Kmat,
                float* __restrict__ out)
{
  const int b    = blockIdx.x;
  const int tid  = threadIdx.x;
  const int lane = tid & 63;
  const int wv   = tid >> 6;

  __shared__ float  red[NWAVE][45];
  __shared__ double sMd[45];
  __shared__ double sLp[45];          // packed LDL^T: off-diag L, diag = d_k
  __shared__ double sDinv[9];         // 1/d_k
  __shared__ double sW[81];           // W = L^{-1} (unit lower): sW[k*9+j] = W[k][j]
  __shared__ double sB[81];           // B = M^{-1}
  __shared__ double sC[81];           // C = B^2
  __shared__ float  sR[21];           // R1(9), R2(9), t(3)
  __shared__ float  sscore[NWAVE][4];

  float Ki0[9], Ki1[9];
  inv3x3f(Kmat + (size_t)b*18,     Ki0);
  inv3x3f(Kmat + (size_t)b*18 + 9, Ki1);

  const float4* k0p4 = (const float4*)(kpts0 + (size_t)b*NPTS*2);
  const float4* k1p4 = (const float4*)(kpts1 + (size_t)b*NPTS*2);
  const float2* cp2  = (const float2*)(conf  + (size_t)b*NPTS);

  // ---------------- Phase 1: load+normalize once, reduce M -----------------
  float px0[PPT][3], px1[PPT][3], pw[PPT];   // kept live into phase 3
  float acc[45];
#pragma unroll
  for (int j=0;j<45;j++) acc[j] = 0.f;

#pragma unroll
  for (int p=0;p<PPT/2;p++) {
    const int idx = tid + p*NT;          // float4 index: 2 points
    const float4 q0 = k0p4[idx];
    const float4 q1 = k1p4[idx];
    const float2 w2 = cp2[idx];
#pragma unroll
    for (int h=0; h<2; h++) {
      const int pt = 2*p + h;
      const float u0 = h ? q0.z : q0.x, v0 = h ? q0.w : q0.y;
      const float u1 = h ? q1.z : q1.x, v1 = h ? q1.w : q1.y;
      const float w  = h ? w2.y : w2.x;
      float x0[3], x1[3];
      x0[0] = fmaf(Ki0[0],u0, fmaf(Ki0[1],v0, Ki0[2]));
      x0[1] = fmaf(Ki0[3],u0, fmaf(Ki0[4],v0, Ki0[5]));
      x0[2] = fmaf(Ki0[6],u0, fmaf(Ki0[7],v0, Ki0[8]));
      x1[0] = fmaf(Ki1[0],u1, fmaf(Ki1[1],v1, Ki1[2]));
      x1[1] = fmaf(Ki1[3],u1, fmaf(Ki1[4],v1, Ki1[5]));
      x1[2] = fmaf(Ki1[6],u1, fmaf(Ki1[7],v1, Ki1[8]));
#pragma unroll
      for (int j=0;j<3;j++) { px0[pt][j] = x0[j]; px1[pt][j] = x1[j]; }
      pw[pt] = w;
      float X[9], wX[9];
#pragma unroll
      for (int ii=0; ii<3; ii++)
#pragma unroll
        for (int jj=0; jj<3; jj++)
          X[ii*3+jj] = x1[ii]*x0[jj];
#pragma unroll
      for (int j=0;j<9;j++) wX[j] = w*X[j];
      int k = 0;
#pragma unroll
      for (int r=0;r<9;r++)
#pragma unroll
        for (int c=r;c<9;c++) { acc[k] = fmaf(wX[r], X[c], acc[k]); k++; }
    }
  }

#pragma unroll
  for (int j=0;j<45;j++) {
    float v = acc[j];
#pragma unroll
    for (int off=32; off>0; off>>=1) v += __shfl_xor(v, off, 64);
    acc[j] = v;
  }
  if (lane == 0) {
#pragma unroll
    for (int j=0;j<45;j++) red[wv][j] = acc[j];
  }
  __syncthreads();   // barrier #1: red[] visible to wave 0

  // ---------------- Phase 2: fp64 solve, entirely on wave 0 ----------------
  if (wv == 0) {
    // cross-wave fp64 combine (unchanged summation order: wq ascending).
    // Moved into wave 0 so the handoff to lane 0 is wave-coherent -- the old
    // block barrier #2 is deleted.
    if (lane < 45) {
      double s = 0.0;
#pragma unroll
      for (int wq=0; wq<NWAVE; wq++) s += (double)red[wq][lane];
      sMd[lane] = s;
    }
    asm volatile("s_waitcnt lgkmcnt(0)" ::: "memory");
    __builtin_amdgcn_sched_barrier(0);

    if (lane == 0) {
      double L[45];
#pragma unroll
      for (int r=0;r<9;r++)
#pragma unroll
        for (int c=0;c<=r;c++)
          L[IDX(r,c)] = sMd[UPIDX(c,r)];

      // LDL^T: M = L D L^T, L unit-lower (packed, in place). No sqrt on the
      // critical path -- one div per column. M PD (lmin ~ 12); guard never
      // fires in practice.
      double dv[9], dinv[9];
#pragma unroll
      for (int k=0;k<9;k++) {
        double s = L[IDX(k,k)];
#pragma unroll
        for (int j=0;j<k;j++) {
          double t = dv[j]*L[IDX(k,j)];
          s -= t*L[IDX(k,j)];
        }
        s = fmax(s, 1e-30);
        dv[k] = s;
        const double di = 1.0/s;
        dinv[k] = di;
#pragma unroll
        for (int i2=k+1;i2<9;i2++) {
          double s2 = L[IDX(i2,k)];
#pragma unroll
          for (int j=0;j<k;j++) s2 -= L[IDX(i2,j)]*(dv[j]*L[IDX(k,j)]);
          L[IDX(i2,k)] = s2*di;
        }
        L[IDX(k,k)] = s;   // store d_k on the diagonal slot (unused by W)
      }
      // publish for the parallel lanes
#pragma unroll
      for (int j=0;j<45;j++) sLp[j] = L[j];
#pragma unroll
      for (int k=0;k<9;k++) sDinv[k] = dinv[k];
    }
    asm volatile("s_waitcnt lgkmcnt(0)" ::: "memory");
    __builtin_amdgcn_sched_barrier(0);

    double Brow[9];
    double Crow[9];
    double vlan[9];
    if (lane < 9) {
      // ---- W = L^{-1} (unit lower), column `lane`, forward substitution ----
      // zero-padded terms are exact +/-0 no-ops; no dinv scaling (unit diag).
      double cw[9];
#pragma unroll
      for (int i=0;i<9;i++) cw[i] = (i == lane) ? 1.0 : 0.0;
#pragma unroll
      for (int i2=1;i2<9;i2++) {
        double s = 0.0;
#pragma unroll
        for (int k=0;k<i2;k++) s = fma(sLp[IDX(i2,k)], cw[k], s);
        cw[i2] = (i2 > lane) ? -s : cw[i2];
      }
#pragma unroll
      for (int k=0;k<9;k++) sW[k*9 + lane] = cw[k];
    }
    asm volatile("s_waitcnt lgkmcnt(0)" ::: "memory");
    __builtin_amdgcn_sched_barrier(0);

    if (lane < 9) {
      // ---- B = W^T D^{-1} W = M^{-1}: row `lane` ----
      double wcol[9];
#pragma unroll
      for (int k=0;k<9;k++) wcol[k] = sW[k*9 + lane]*sDinv[k];
#pragma unroll
      for (int j=0;j<9;j++) {
        double s = 0.0;
#pragma unroll
        for (int k=0;k<9;k++) s = fma(wcol[k], sW[k*9 + j], s);
        Brow[j] = s;
      }
#pragma unroll
      for (int j=0;j<9;j++) sB[lane*9 + j] = Brow[j];
    }
    asm volatile("s_waitcnt lgkmcnt(0)" ::: "memory");
    __builtin_amdgcn_sched_barrier(0);

    if (lane < 9) {
      // ---- C = B*B, row `lane` ----
#pragma unroll
      for (int j=0;j<9;j++) {
        double s = 0.0;
#pragma unroll
        for (int k=0;k<9;k++) s = fma(Brow[k], sB[k*9 + j], s);
        Crow[j] = s;
      }
#pragma unroll
      for (int j=0;j<9;j++) sC[lane*9 + j] = Crow[j];
    }
    asm volatile("s_waitcnt lgkmcnt(0)" ::: "memory");
    __builtin_amdgcn_sched_barrier(0);

    if (lane < 9) {
      // ---- D = C*C = B^4, row `lane`; then v <- D^5 v  (== B^20 v) ----
      double Drow[9];
#pragma unroll
      for (int j=0;j<9;j++) {
        double s = 0.0;
#pragma unroll
        for (int k=0;k<9;k++) s = fma(Crow[k], sC[k*9 + j], s);
        Drow[j] = s;
      }

      // 5 inverse-power rounds; tree dot cuts per-round latency. No renorm:
      // fp64 exponent absorbs the shrink (|v| ~ 1e-22, no underflow).
      double vv[9];
#pragma unroll
      for (int j=0;j<9;j++) vv[j] = 0.125;
      vv[4] = 1.0;
      for (int it=0; it<5; ++it) {
        double p0 = fma(Drow[1], vv[1], Drow[0]*vv[0]);
        double p1 = fma(Drow[3], vv[3], Drow[2]*vv[2]);
        double p2 = fma(Drow[5], vv[5], Drow[4]*vv[4]);
        double p3 = fma(Drow[7], vv[7], Drow[6]*vv[6]);
        double p4 = Drow[8]*vv[8];
        double y  = ((p0 + p1) + (p2 + p3)) + p4;
#pragma unroll
        for (int j=0;j<9;j++) vv[j] = __shfl(y, j, 64);
      }
#pragma unroll
      for (int j=0;j<9;j++) vlan[j] = vv[j];
    }

    if (lane == 0) {
      // ---- serial tail: Jacobi, U, R. v left UNNORMALIZED (scale-free:
      // tau is a ratio, guard is relative, u1/u2 renormalized, |v|^2 ~ 1e-44
      // >> denormal floor; CSWAP compares uniformly-scaled lam). ----
      double v[9];
#pragma unroll
      for (int j=0;j<9;j++) v[j] = vlan[j];

      // E = reshape(v,3,3); SVD: Jacobi on G=E^T E -> V; U via projection+cross
      double E0[3][3];
#pragma unroll
      for (int ii=0;ii<3;ii++)
#pragma unroll
        for (int jj=0;jj<3;jj++) E0[ii][jj] = v[ii*3+jj];
      double G[3][3];
#pragma unroll
      for (int a2=0;a2<3;a2++)
#pragma unroll
        for (int b2=0;b2<3;b2++)
          G[a2][b2] = E0[0][a2]*E0[0][b2] + E0[1][a2]*E0[1][b2] + E0[2][a2]*E0[2][b2];
      double Vv[3][3] = {{1,0,0},{0,1,0},{0,0,1}};
      // RELATIVE skip guard (1e-18): sub-ULP rotations skipped; quadratic
      // convergence makes sweeps ~4-6 all skips (cheap checks only).
#define JROT(P,Q,RR) do { \
      double apq = G[P][Q]; \
      if (fabs(apq) > 1e-18*(fabs(G[P][P])+fabs(G[Q][Q]))) { \
        double app = G[P][P], aqq = G[Q][Q]; \
        double tau = (aqq - app) / (2.0*apq); \
        double tt = ((tau >= 0.0) ? 1.0 : -1.0) / (fabs(tau) + sqrt(1.0 + tau*tau)); \
        double cc_ = 1.0/sqrt(1.0 + tt*tt); \
        double ss_ = tt*cc_; \
        G[P][P] = app - tt*apq; \
        G[Q][Q] = aqq + tt*apq; \
        G[P][Q] = 0.0; G[Q][P] = 0.0; \
        double grp = G[RR][P], grq = G[RR][Q]; \
        G[RR][P] = cc_*grp - ss_*grq; G[P][RR] = G[RR][P]; \
        G[RR][Q] = ss_*grp + cc_*grq; G[Q][RR] = G[RR][Q]; \
        double v0p = Vv[0][P], v0q = Vv[0][Q]; \
        Vv[0][P] = cc_*v0p - ss_*v0q; Vv[0][Q] = ss_*v0p + cc_*v0q; \
        double v1p = Vv[1][P], v1q = Vv[1][Q]; \
        Vv[1][P] = cc_*v1p - ss_*v1q; Vv[1][Q] = ss_*v1p + cc_*v1q; \
        double v2p = Vv[2][P], v2q = Vv[2][Q]; \
        Vv[2][P] = cc_*v2p - ss_*v2q; Vv[2][Q] = ss_*v2p + cc_*v2q; \
      } } while(0)
      for (int sw=0; sw<6; sw++) { JROT(0,1,2); JROT(0,2,1); JROT(1,2,0); }
#undef JROT
      double lam[3] = {G[0][0], G[1][1], G[2][2]};
#define CSWAP(A_,B_) if (lam[A_] < lam[B_]) { \
      double tl = lam[A_]; lam[A_] = lam[B_]; lam[B_] = tl; \
      double t0_ = Vv[0][A_]; Vv[0][A_] = Vv[0][B_]; Vv[0][B_] = t0_; \
      double t1_ = Vv[1][A_]; Vv[1][A_] = Vv[1][B_]; Vv[1][B_] = t1_; \
      double t2_ = Vv[2][A_]; Vv[2][A_] = Vv[2][B_]; Vv[2][B_] = t2_; }
      CSWAP(0,1); CSWAP(0,2); CSWAP(1,2);
#undef CSWAP
      double u1[3], u2[3], u3[3];
#pragma unroll
      for (int i3=0;i3<3;i3++)
        u1[i3] = E0[i3][0]*Vv[0][0] + E0[i3][1]*Vv[1][0] + E0[i3][2]*Vv[2][0];
      double n1 = 1.0/sqrt(fmax(u1[0]*u1[0]+u1[1]*u1[1]+u1[2]*u1[2], 1e-300));
#pragma unroll
      for (int i3=0;i3<3;i3++) u1[i3] *= n1;
#pragma unroll
      for (int i3=0;i3<3;i3++)
        u2[i3] = E0[i3][0]*Vv[0][1] + E0[i3][1]*Vv[1][1] + E0[i3][2]*Vv[2][1];
      double d12 = u1[0]*u2[0]+u1[1]*u2[1]+u1[2]*u2[2];
#pragma unroll
      for (int i3=0;i3<3;i3++) u2[i3] -= d12*u1[i3];
      double n2 = 1.0/sqrt(fmax(u2[0]*u2[0]+u2[1]*u2[1]+u2[2]*u2[2], 1e-300));
#pragma unroll
      for (int i3=0;i3<3;i3++) u2[i3] *= n2;
      u3[0] = u1[1]*u2[2] - u1[2]*u2[1];
      u3[1] = u1[2]*u2[0] - u1[0]*u2[2];
      u3[2] = u1[0]*u2[1] - u1[1]*u2[0];
      // U W V^T = [u2,-u1,u3] V^T ;  U W^T V^T = [-u2,u1,u3] V^T
      double R1a[9], R2a[9];
#pragma unroll
      for (int i3=0;i3<3;i3++)
#pragma unroll
        for (int j3=0;j3<3;j3++) {
          double m  = u3[i3]*Vv[j3][2];
          double pA = u2[i3]*Vv[j3][0] - u1[i3]*Vv[j3][1];
          R1a[i3*3+j3] = pA + m;
          R2a[i3*3+j3] = m - pA;
        }
      double det1 = R1a[0]*(R1a[4]*R1a[8]-R1a[5]*R1a[7])
                  - R1a[1]*(R1a[3]*R1a[8]-R1a[5]*R1a[6])
                  + R1a[2]*(R1a[3]*R1a[7]-R1a[4]*R1a[6]);
      double det2 = R2a[0]*(R2a[4]*R2a[8]-R2a[5]*R2a[7])
                  - R2a[1]*(R2a[3]*R2a[8]-R2a[5]*R2a[6])
                  + R2a[2]*(R2a[3]*R2a[7]-R2a[4]*R2a[6]);
      double sg1 = (det1 < 0.0) ? -1.0 : 1.0;
      double sg2 = (det2 < 0.0) ? -1.0 : 1.0;
#pragma unroll
      for (int j3=0;j3<9;j3++) { sR[j3] = (float)(sg1*R1a[j3]); sR[9+j3] = (float)(sg2*R2a[j3]); }
      sR[18] = (float)u3[0]; sR[19] = (float)u3[1]; sR[20] = (float)u3[2];
    }
  }
  __syncthreads();   // sR visible to all waves

  // ---------------- Phase 3: cheirality scores from registers --------------
  float r1[9], r2[9], tv[3];
#pragma unroll
  for (int j=0;j<9;j++) { r1[j] = sR[j]; r2[j] = sR[9+j]; }
  tv[0] = sR[18]; tv[1] = sR[19]; tv[2] = sR[20];

  float sc[4] = {0.f, 0.f, 0.f, 0.f};
#pragma unroll
  for (int p=0;p<PPT;p++) {
    const float x00 = px0[p][0], x01 = px0[p][1], x02 = px0[p][2];
    const float x10 = px1[p][0], x11 = px1[p][1], x12 = px1[p][2];
    const float w   = pw[p];
    const float bb2 = x10*x10 + x11*x11 + x12*x12;
    const float bt  = x10*tv[0] + x11*tv[1] + x12*tv[2];
    {
      float a0 = r1[0]*x00 + r1[1]*x01 + r1[2]*x02;
      float a1 = r1[3]*x00 + r1[4]*x01 + r1[5]*x02;
      float a2 = r1[6]*x00 + r1[7]*x01 + r1[8]*x02;
      float aa = a0*a0 + a1*a1 + a2*a2;
      float ab = a0*x10 + a1*x11 + a2*x12;
      float at = a0*tv[0] + a1*tv[1] + a2*tv[2];
      float n0v = ab*bt - at*bb2;     // d0*det (det>0)
      float n1v = aa*bt - ab*at;      // d1*det
      if (n0v > 0.f && n1v > 0.f) sc[0] += w;    // (R1,+t)
      if (n0v < 0.f && n1v < 0.f) sc[1] += w;    // (R1,-t)
    }
    {
      float a0 = r2[0]*x00 + r2[1]*x01 + r2[2]*x02;
      float a1 = r2[3]*x00 + r2[4]*x01 + r2[5]*x02;
      float a2 = r2[6]*x00 + r2[7]*x01 + r2[8]*x02;
      float aa = a0*a0 + a1*a1 + a2*a2;
      float ab = a0*x10 + a1*x11 + a2*x12;
      float at = a0*tv[0] + a1*tv[1] + a2*tv[2];
      float n0v = ab*bt - at*bb2;
      float n1v = aa*bt - ab*at;
      if (n0v > 0.f && n1v > 0.f) sc[2] += w;    // (R2,+t)
      if (n0v < 0.f && n1v < 0.f) sc[3] += w;    // (R2,-t)
    }
  }
#pragma unroll
  for (int c=0;c<4;c++) {
    float vv = sc[c];
#pragma unroll
    for (int off=32; off>0; off>>=1) vv += __shfl_xor(vv, off, 64);
    sc[c] = vv;
  }
  if (lane == 0) {
#pragma unroll
    for (int c=0;c<4;c++) sscore[wv][c] = sc[c];
  }
  __syncthreads();

  // ---------------- Phase 4 (tid 0): argmax + assemble T01/T10 -------------
  if (tid == 0) {
    float st[4];
#pragma unroll
    for (int c=0;c<4;c++) {
      float s = 0.f;
#pragma unroll
      for (int wq=0; wq<NWAVE; wq++) s += sscore[wq][c];
      st[c] = s;
    }
    int bestc = 0; float bs = st[0];
    if (st[1] > bs) { bs = st[1]; bestc = 1; }   // strict > keeps first on tie
    if (st[2] > bs) { bs = st[2]; bestc = 2; }
    if (st[3] > bs) { bs = st[3]; bestc = 3; }
    float Rb[9];
#pragma unroll
    for (int j=0;j<9;j++) Rb[j] = (bestc < 2) ? r1[j] : r2[j];
    const float sg = (bestc & 1) ? -1.f : 1.f;
    const float ts = t_scale[(size_t)b*2];
    const float t0 = sg*tv[0]*ts, t1 = sg*tv[1]*ts, t2 = sg*tv[2]*ts;
    float* o = out + (size_t)b*32;
    // T01 = [R | t_sc ; 0 0 0 1]
    o[0]=Rb[0]; o[1]=Rb[1]; o[2] =Rb[2]; o[3] =t0;
    o[4]=Rb[3]; o[5]=Rb[4]; o[6] =Rb[5]; o[7] =t1;
    o[8]=Rb[6]; o[9]=Rb[7]; o[10]=Rb[8]; o[11]=t2;
    o[12]=0.f; o[13]=0.f; o[14]=0.f; o[15]=1.f;
    // T10 = [R^T | -R^T t_sc ; 0 0 0 1]
    const float ti0 = -(Rb[0]*t0 + Rb[3]*t1 + Rb[6]*t2);
    const float ti1 = -(Rb[1]*t0 + Rb[4]*t1 + Rb[7]*t2);
    const float ti2 = -(Rb[2]*t0 + Rb[5]*t1 + Rb[8]*t2);
    o[16]=Rb[0]; o[17]=Rb[3]; o[18]=Rb[6]; o[19]=ti0;
    o[20]=Rb[1]; o[21]=Rb[4]; o[22]=Rb[7]; o[23]=ti1;
    o[24]=Rb[2]; o[25]=Rb[5]; o[26]=Rb[8]; o[27]=ti2;
    o[28]=0.f; o[29]=0.f; o[30]=0.f; o[31]=1.f;
  }
}

// ===========================================================================
extern "C" void kernel_launch(void* const* d_in, const int* in_sizes, int n_in,
                              void* d_out, int out_size, void* d_ws, size_t ws_size,
                              hipStream_t stream) {
  (void)in_sizes; (void)n_in; (void)out_size; (void)d_ws; (void)ws_size;
  const float* kpts0  = (const float*)d_in[0];
  const float* kpts1  = (const float*)d_in[1];
  const float* conf   = (const float*)d_in[2];
  const float* tscale = (const float*)d_in[3];
  const float* K      = (const float*)d_in[4];
  float* outp = (float*)d_out;
  pose_fused<<<dim3(NBATCH), dim3(NT), 0, stream>>>(kpts0, kpts1, conf, tscale, K, outp);
}